// Round 2
// baseline (1633.873 us; speedup 1.0000x reference)
//
#include <hip/hip_runtime.h>
#include <hip/hip_bf16.h>

typedef __attribute__((ext_vector_type(8))) short bf16x8;
typedef __attribute__((ext_vector_type(4))) float f32x4;

#define L_SZ 1024
#define D_SZ 64
#define SCALE 0.125f

// Score/P exchange buffer: [b_local 32][q 16][k 32], padded
#define KP 36            // k-pitch (floats)
#define BP 580           // b-pitch = 16*KP + 4
#define SA_F 18560       // 32*BP floats = 74.2 KB
#define OD 68            // epilogue Obuf d-pitch

// ws layout: Oacc f32[64*1024*64] @0 (16777216 B), Lacc f32[64*1024] @16777216,
//            Vt bf16[64*64*1024] @17039360. Total 25.4 MB.
#define OACC_BYTES 16777216
#define LACC_BYTES 262144
#define VT_OFF 17039360

__device__ __forceinline__ short f2bf(float f) {
    union { float f; unsigned u; } v; v.f = f;
    unsigned r = (v.u + 0x7fffu + ((v.u >> 16) & 1u)) >> 16;  // RNE
    return (short)r;
}

__device__ __forceinline__ bf16x8 cvt8(const float* __restrict__ p) {
    f32x4 a = *(const f32x4*)p;
    f32x4 b = *(const f32x4*)(p + 4);
    bf16x8 r;
    r[0] = f2bf(a[0]); r[1] = f2bf(a[1]); r[2] = f2bf(a[2]); r[3] = f2bf(a[3]);
    r[4] = f2bf(b[0]); r[5] = f2bf(b[1]); r[6] = f2bf(b[2]); r[7] = f2bf(b[3]);
    return r;
}

#define MFMA(A, Bf, C) __builtin_amdgcn_mfma_f32_16x16x32_bf16(A, Bf, C, 0, 0, 0)

__global__ void zero_ws(float* __restrict__ p, int n4) {
    int i = blockIdx.x * 256 + threadIdx.x;
    if (i < n4) ((f32x4*)p)[i] = (f32x4){0.f, 0.f, 0.f, 0.f};
}

// Vt[b][d][k] = bf16(V[b][k][d])
__global__ void transpose_v(const float* __restrict__ V, unsigned short* __restrict__ Vt) {
    __shared__ float T[64][65];
    const int b = blockIdx.y, k0 = blockIdx.x * 64;
    const int t = threadIdx.x;
    {
        const int kl = t >> 2, dq = (t & 3) * 16;
        const float* src = V + (b * L_SZ + k0 + kl) * D_SZ + dq;
#pragma unroll
        for (int j = 0; j < 16; j += 4) {
            f32x4 v = *(const f32x4*)(src + j);
            T[kl][dq + j] = v[0]; T[kl][dq + j + 1] = v[1];
            T[kl][dq + j + 2] = v[2]; T[kl][dq + j + 3] = v[3];
        }
    }
    __syncthreads();
    {
        const int d = t >> 2, kq = (t & 3) * 16;
        bf16x8 o0, o1;
#pragma unroll
        for (int j = 0; j < 8; ++j) o0[j] = f2bf(T[kq + j][d]);
#pragma unroll
        for (int j = 0; j < 8; ++j) o1[j] = f2bf(T[kq + 8 + j][d]);
        unsigned short* dst = Vt + (b * D_SZ + d) * L_SZ + k0 + kq;
        *(bf16x8*)dst = o0;
        *(bf16x8*)(dst + 8) = o1;
    }
}

// Block: 512 thr = 8 waves. Tile: 32 batches x 16 queries x 256 keys.
// Content: wave owns 4 b. Pos: wave owns 2 q. k-chunk 32 per iteration.
__global__ __launch_bounds__(512, 2) void rpr_main(
    const float* __restrict__ Q, const float* __restrict__ K,
    const float* __restrict__ PK, const float* __restrict__ PV,
    const int* __restrict__ VLEN, const unsigned short* __restrict__ Vt,
    float* __restrict__ Oacc, float* __restrict__ Lacc)
{
    __shared__ float SA[SA_F];
    const int tid = threadIdx.x;
    const int wave = tid >> 6, lane = tid & 63;
    const int lane15 = lane & 15, quad = lane >> 4;
    // id -> (group g, b-half m); the two m's of a group differ by 8 in id -> same XCD
    const int id = blockIdx.x;
    const int g = (id & 7) | ((id >> 4) << 3);   // 0..255
    const int m = (id >> 3) & 1;
    const int q0 = (g >> 2) << 4;                // 64 q-tiles
    const int kbase = (g & 3) << 8;              // 4 k-splits of 256
    const int b0 = m << 5;                       // b-half

    // ---- Q fragments ----
    bf16x8 qa[4][2];        // content: [j=b][dhalf], A[m=q][k=d]
    int vl[4];
#pragma unroll
    for (int j = 0; j < 4; ++j) {
        const int b = b0 + wave * 4 + j;
        vl[j] = VLEN[b];
        const float* p = Q + (b * L_SZ + q0 + lane15) * D_SZ + quad * 8;
        qa[j][0] = cvt8(p); qa[j][1] = cvt8(p + 32);
    }
    bf16x8 qp[2][2][2];     // pos: [j=q][mtile(b16)][dhalf], A[m=b][k=d]
#pragma unroll
    for (int j = 0; j < 2; ++j) {
        const int q = q0 + wave * 2 + j;
#pragma unroll
        for (int mt = 0; mt < 2; ++mt) {
            const float* p = Q + ((b0 + mt * 16 + lane15) * L_SZ + q) * D_SZ + quad * 8;
            qp[j][mt][0] = cvt8(p); qp[j][mt][1] = cvt8(p + 32);
        }
    }

    f32x4 Oc[4][4];         // content O: [j=b][nt=d16]
    f32x4 Op[2][2][4];      // pos O:     [j=q][mtile=b16][nt=d16]
#pragma unroll
    for (int j = 0; j < 4; ++j)
#pragma unroll
        for (int nt = 0; nt < 4; ++nt) Oc[j][nt] = (f32x4){0.f, 0.f, 0.f, 0.f};
#pragma unroll
    for (int j = 0; j < 2; ++j)
#pragma unroll
        for (int mt = 0; mt < 2; ++mt)
#pragma unroll
            for (int nt = 0; nt < 4; ++nt) Op[j][mt][nt] = (f32x4){0.f, 0.f, 0.f, 0.f};
    float l_acc = 0.f;
    const int row_b = tid >> 4, row_q = tid & 15;   // this thread's l-sum row

    for (int it = 0; it < 8; ++it) {
        const int kb = kbase + it * 32;

        // ---- P1: pos scores S_p[q](b32 x k32) -> SA[b][q][k] ----
#pragma unroll
        for (int j = 0; j < 2; ++j) {
            const int ql = wave * 2 + j;
            const int q = q0 + ql;
#pragma unroll
            for (int nt = 0; nt < 2; ++nt) {
                const float* bp = PK + (q * L_SZ + kb + nt * 16 + lane15) * D_SZ + quad * 8;
                bf16x8 f0 = cvt8(bp), f1 = cvt8(bp + 32);
#pragma unroll
                for (int mt = 0; mt < 2; ++mt) {
                    f32x4 acc = (f32x4){0.f, 0.f, 0.f, 0.f};
                    acc = MFMA(qp[j][mt][0], f0, acc);
                    acc = MFMA(qp[j][mt][1], f1, acc);
                    const int base = (mt * 16 + quad * 4) * BP + ql * KP + nt * 16 + lane15;
#pragma unroll
                    for (int i = 0; i < 4; ++i) SA[base + i * BP] = acc[i];
                }
            }
        }
        __syncthreads();

        // ---- P2: content scores + combine + mask + exp (in-place) ----
#pragma unroll
        for (int j = 0; j < 4; ++j) {
            const int bl = wave * 4 + j;
            const int b = b0 + bl;
#pragma unroll
            for (int nt = 0; nt < 2; ++nt) {
                const float* bp = K + (b * L_SZ + kb + nt * 16 + lane15) * D_SZ + quad * 8;
                f32x4 acc = (f32x4){0.f, 0.f, 0.f, 0.f};
                acc = MFMA(qa[j][0], cvt8(bp), acc);
                acc = MFMA(qa[j][1], cvt8(bp + 32), acc);
                const int kg = kb + nt * 16 + lane15;
                const int base = bl * BP + quad * 4 * KP + nt * 16 + lane15;
#pragma unroll
                for (int i = 0; i < 4; ++i) {
                    const int idx = base + i * KP;
                    const float s = (acc[i] + SA[idx]) * SCALE;
                    float e;
                    if (vl[j] == 0)      e = 1.0f;
                    else if (kg < vl[j]) e = __expf(s);
                    else                 e = 0.0f;
                    SA[idx] = e;
                }
            }
        }
        __syncthreads();

        // ---- P3: l-sum + content PV + pos PV ----
        {
            const float* row = SA + row_b * BP + row_q * KP;
            float s = 0.f;
#pragma unroll
            for (int kk = 0; kk < 32; kk += 4) {
                f32x4 v = *(const f32x4*)(row + kk);
                s += v[0] + v[1] + v[2] + v[3];
            }
            l_acc += s;
        }
#pragma unroll
        for (int j = 0; j < 4; ++j) {
            const int bl = wave * 4 + j;
            const int b = b0 + bl;
            const bf16x8 af = cvt8(SA + bl * BP + lane15 * KP + quad * 8);
#pragma unroll
            for (int nt = 0; nt < 4; ++nt) {
                const bf16x8 bf = *(const bf16x8*)(Vt + (b * D_SZ + nt * 16 + lane15) * L_SZ + kb + quad * 8);
                Oc[j][nt] = MFMA(af, bf, Oc[j][nt]);
            }
        }
#pragma unroll
        for (int j = 0; j < 2; ++j) {
            const int ql = wave * 2 + j;
            const int q = q0 + ql;
            const bf16x8 a0 = cvt8(SA + lane15 * BP + ql * KP + quad * 8);
            const bf16x8 a1 = cvt8(SA + (16 + lane15) * BP + ql * KP + quad * 8);
            const float* pvb = PV + (q * L_SZ + kb + quad * 8) * D_SZ + lane15;
#pragma unroll
            for (int nt = 0; nt < 4; ++nt) {
                bf16x8 bf;
#pragma unroll
                for (int jj = 0; jj < 8; ++jj) bf[jj] = f2bf(pvb[jj * D_SZ + nt * 16]);
                Op[j][0][nt] = MFMA(a0, bf, Op[j][0][nt]);
                Op[j][1][nt] = MFMA(a1, bf, Op[j][1][nt]);
            }
        }
        __syncthreads();
    }

    // ---- epilogue: LDS-merge content+pos per b-half of 16, then atomic flush ----
    float* Ob = SA;
#pragma unroll
    for (int h = 0; h < 2; ++h) {
        if ((wave >> 2) == h) {
#pragma unroll
            for (int j = 0; j < 4; ++j) {
                const int ob = (wave & 3) * 4 + j;
#pragma unroll
                for (int nt = 0; nt < 4; ++nt)
#pragma unroll
                    for (int i = 0; i < 4; ++i)
                        Ob[ob * (16 * OD) + (quad * 4 + i) * OD + nt * 16 + lane15] = Oc[j][nt][i];
            }
        }
        __syncthreads();
#pragma unroll
        for (int j = 0; j < 2; ++j) {
            const int ql = wave * 2 + j;
#pragma unroll
            for (int nt = 0; nt < 4; ++nt)
#pragma unroll
                for (int i = 0; i < 4; ++i)
                    Ob[(quad * 4 + i) * (16 * OD) + ql * OD + nt * 16 + lane15] += Op[j][h][nt][i];
        }
        __syncthreads();
        {
            const int pair = tid >> 1, ob = pair >> 4, oq = pair & 15, ds = (tid & 1) * 32;
            float* dst = Oacc + ((b0 + h * 16 + ob) * L_SZ + q0 + oq) * D_SZ + ds;
            const float* srcp = Ob + ob * (16 * OD) + oq * OD + ds;
#pragma unroll
            for (int dd = 0; dd < 32; ++dd) atomicAdd(dst + dd, srcp[dd]);
        }
        __syncthreads();
    }
    atomicAdd(&Lacc[(b0 + row_b) * L_SZ + q0 + row_q], l_acc);
}

__global__ void norm_out(const float* __restrict__ Oacc, const float* __restrict__ Lacc,
                         float* __restrict__ OUT) {
    const int i4 = blockIdx.x * 256 + threadIdx.x;   // over 1,048,576 f32x4
    f32x4 o = ((const f32x4*)Oacc)[i4];
    const float rl = 1.0f / Lacc[i4 >> 4];
    o[0] *= rl; o[1] *= rl; o[2] *= rl; o[3] *= rl;
    ((f32x4*)OUT)[i4] = o;
}

extern "C" void kernel_launch(void* const* d_in, const int* in_sizes, int n_in,
                              void* d_out, int out_size, void* d_ws, size_t ws_size,
                              hipStream_t stream) {
    (void)in_sizes; (void)n_in; (void)out_size; (void)ws_size;
    const float* Q  = (const float*)d_in[0];
    const float* K  = (const float*)d_in[1];
    const float* V  = (const float*)d_in[2];
    const float* PK = (const float*)d_in[3];
    const float* PV = (const float*)d_in[4];
    const int*   VL = (const int*)d_in[5];
    float* OUT = (float*)d_out;

    float* Oacc = (float*)d_ws;
    float* Lacc = (float*)((char*)d_ws + OACC_BYTES);
    unsigned short* Vt = (unsigned short*)((char*)d_ws + VT_OFF);

    zero_ws<<<4160, 256, 0, stream>>>((float*)d_ws, (OACC_BYTES + LACC_BYTES) / 16);
    transpose_v<<<dim3(16, 64), 256, 0, stream>>>(V, Vt);
    rpr_main<<<512, 512, 0, stream>>>(Q, K, PK, PV, VL, Vt, Oacc, Lacc);
    norm_out<<<4096, 256, 0, stream>>>(Oacc, Lacc, OUT);
}